// Round 5
// baseline (29.787 us; speedup 1.0000x reference)
//
#include <hip/hip_runtime.h>
#include <math.h>

#define N_PTS 1024
#define D 128
#define QL 400
#define PLD 1200            // 3*QL
#define SQRT_D_INV 0.08838834764831845f

typedef __attribute__((ext_vector_type(8))) short bf16x8;
typedef __attribute__((ext_vector_type(4))) float f32x4;
typedef unsigned short u16;

#define GLOBAL_AS __attribute__((address_space(1)))
#define LDS_AS    __attribute__((address_space(3)))

__device__ __forceinline__ u16 f2bf(float x) {
    union { float f; unsigned u; } v; v.f = x;
    unsigned r = v.u + 0x7fff + ((v.u >> 16) & 1);   // RNE
    return (u16)(r >> 16);
}
__device__ __forceinline__ float b2f(u16 h) {
    union { unsigned u; float f; } v; v.u = ((unsigned)h) << 16;
    return v.f;
}

// ------------------------------------------------------------------
// prep_all: ONE dispatch, two roles, no cross-block deps.
//  blocks [0,304): P-role. tile (ib,jb) of Pb = (k @ Tcat^T)*1/sqrt(D).
//    k-tile recomputed locally from features@W[:,128:256]+b;
//    Tcat tile converted locally from f32 tables.
//  blocks [304,400): qkv-role. qkv = features@W+b -> qb(scaled)/kb/vT.
// ------------------------------------------------------------------
__global__ __launch_bounds__(256) void prep_all_kernel(
    const float* __restrict__ features, const float* __restrict__ W,
    const float* __restrict__ bias,
    const float* __restrict__ tx, const float* __restrict__ ty,
    const float* __restrict__ tz,
    u16* __restrict__ qb, u16* __restrict__ kb, u16* __restrict__ vT,
    u16* __restrict__ Pb)
{
    __shared__ __align__(16) u16 smem[24576];    // 48 KB
    u16* As = smem;            // 8192 u16: features / qkv-A / k-tile alias
    u16* Bs = smem + 8192;     // 16384 u16: W chunk; Tcat tile aliases front

    const int tid = threadIdx.x;
    const int bx = blockIdx.x;
    const int wave = tid >> 6, lane = tid & 63;
    const int wr = wave >> 1, wc = wave & 1;
    const int l15 = lane & 15, l4 = lane >> 4;

    if (bx >= 304) {
        // ---------------- qkv role ----------------
        const int qx = bx - 304;
        const int bm = (qx / 6) * 64;
        const int bn = (qx % 6) * 64;

        #pragma unroll
        for (int r0 = 0; r0 < 4; ++r0) {
            int unit = r0 * 256 + tid;
            int row = unit >> 4, c16 = unit & 15;
            const float* ga = features + (size_t)(bm + row) * D + c16 * 8;
            float4 a0 = *(const float4*)ga;
            float4 a1 = *(const float4*)(ga + 4);
            u16 h[8] = {f2bf(a0.x), f2bf(a0.y), f2bf(a0.z), f2bf(a0.w),
                        f2bf(a1.x), f2bf(a1.y), f2bf(a1.z), f2bf(a1.w)};
            *(bf16x8*)(As + row * 128 + ((c16 ^ (row & 7)) * 8)) = *(bf16x8*)h;
        }
        #pragma unroll
        for (int r2 = 0; r2 < 8; ++r2) {
            int k = r2 * 16 + (tid >> 4);
            int nl = (tid & 15) * 4;
            float4 w4 = *(const float4*)&W[(size_t)k * 384 + bn + nl];
            float wv[4] = {w4.x, w4.y, w4.z, w4.w};
            #pragma unroll
            for (int e = 0; e < 4; ++e) {
                int n = nl + e;
                Bs[n * 128 + (((k >> 3) ^ (n & 7)) << 3) + (k & 7)] = f2bf(wv[e]);
            }
        }
        __syncthreads();

        f32x4 acc[2][2] = {};
        #pragma unroll
        for (int ks = 0; ks < 4; ++ks) {
            bf16x8 a[2], b[2];
            #pragma unroll
            for (int m = 0; m < 2; ++m) {
                int row = wr * 32 + m * 16 + l15;
                int c16 = ks * 4 + l4;
                a[m] = *(const bf16x8*)(As + row * 128 + ((c16 ^ (row & 7)) * 8));
            }
            #pragma unroll
            for (int n = 0; n < 2; ++n) {
                int row = wc * 32 + n * 16 + l15;
                int c16 = ks * 4 + l4;
                b[n] = *(const bf16x8*)(Bs + row * 128 + ((c16 ^ (row & 7)) * 8));
            }
            #pragma unroll
            for (int m = 0; m < 2; ++m)
                #pragma unroll
                for (int n = 0; n < 2; ++n)
                    acc[m][n] = __builtin_amdgcn_mfma_f32_16x16x32_bf16(
                        a[m], b[n], acc[m][n], 0, 0, 0);
        }

        #pragma unroll
        for (int m = 0; m < 2; ++m)
            #pragma unroll
            for (int n = 0; n < 2; ++n)
                #pragma unroll
                for (int r = 0; r < 4; ++r) {
                    int grow = bm + wr * 32 + m * 16 + l4 * 4 + r;
                    int gcol = bn + wc * 32 + n * 16 + l15;
                    float val = acc[m][n][r] + bias[gcol];
                    int reg = gcol >> 7, lc = gcol & 127;
                    if (reg == 0)      qb[grow * D + lc] = f2bf(val * SQRT_D_INV);
                    else if (reg == 1) kb[grow * D + lc] = f2bf(val);
                    else               vT[(size_t)lc * N_PTS + grow] = f2bf(val);
                }
        return;
    }

    // ---------------- P role ----------------
    const int jb = bx % 19, ib = bx / 19;
    const int bm = ib * 64, bn = jb * 64;

    // phase 1: stage features tile + W k-chunk (cols 128..255)
    #pragma unroll
    for (int r0 = 0; r0 < 4; ++r0) {
        int unit = r0 * 256 + tid;
        int row = unit >> 4, c16 = unit & 15;
        const float* ga = features + (size_t)(bm + row) * D + c16 * 8;
        float4 a0 = *(const float4*)ga;
        float4 a1 = *(const float4*)(ga + 4);
        u16 h[8] = {f2bf(a0.x), f2bf(a0.y), f2bf(a0.z), f2bf(a0.w),
                    f2bf(a1.x), f2bf(a1.y), f2bf(a1.z), f2bf(a1.w)};
        *(bf16x8*)(As + row * 128 + ((c16 ^ (row & 7)) * 8)) = *(bf16x8*)h;
    }
    #pragma unroll
    for (int r2 = 0; r2 < 16; ++r2) {
        int kk = r2 * 8 + (tid >> 5);
        int nl = (tid & 31) * 4;
        float4 w4 = *(const float4*)&W[(size_t)kk * 384 + 128 + nl];
        float wv[4] = {w4.x, w4.y, w4.z, w4.w};
        #pragma unroll
        for (int e = 0; e < 4; ++e) {
            int n = nl + e;
            Bs[n * 128 + (((kk >> 3) ^ (n & 7)) << 3) + (kk & 7)] = f2bf(wv[e]);
        }
    }
    __syncthreads();

    // GEMM1: k-tile (64 x 128) ; wave computes 32 rows x 64 cols
    f32x4 acc1[2][4] = {};
    #pragma unroll
    for (int ks = 0; ks < 4; ++ks) {
        bf16x8 a[2], b[4];
        #pragma unroll
        for (int m = 0; m < 2; ++m) {
            int row = wr * 32 + m * 16 + l15;
            int c16 = ks * 4 + l4;
            a[m] = *(const bf16x8*)(As + row * 128 + ((c16 ^ (row & 7)) * 8));
        }
        #pragma unroll
        for (int n = 0; n < 4; ++n) {
            int row = wc * 64 + n * 16 + l15;
            int c16 = ks * 4 + l4;
            b[n] = *(const bf16x8*)(Bs + row * 128 + ((c16 ^ (row & 7)) * 8));
        }
        #pragma unroll
        for (int m = 0; m < 2; ++m)
            #pragma unroll
            for (int n = 0; n < 4; ++n)
                acc1[m][n] = __builtin_amdgcn_mfma_f32_16x16x32_bf16(
                    a[m], b[n], acc1[m][n], 0, 0, 0);
    }
    __syncthreads();   // all reads of As/Bs done before overwrite

    // epilogue1: k-tile -> As (swizzled bf16), Tcat tile -> Bs front
    #pragma unroll
    for (int m = 0; m < 2; ++m)
        #pragma unroll
        for (int n = 0; n < 4; ++n)
            #pragma unroll
            for (int r = 0; r < 4; ++r) {
                int lrow = wr * 32 + m * 16 + l4 * 4 + r;
                int lcol = wc * 64 + n * 16 + l15;
                float val = acc1[m][n][r] + bias[128 + lcol];
                As[lrow * 128 + (((lcol >> 3) ^ (lrow & 7)) << 3) + (lcol & 7)] =
                    f2bf(val);
            }
    #pragma unroll
    for (int r0 = 0; r0 < 8; ++r0) {
        int e0 = (r0 * 256 + tid) * 4;
        int trow = e0 >> 7, tcol = e0 & 127;
        int grow = bn + trow; if (grow > PLD - 1) grow = PLD - 1;
        int sec = grow / QL, rr = grow - sec * QL;
        const float* t = (sec == 0) ? tx : ((sec == 1) ? ty : tz);
        float4 v = *(const float4*)&t[QL * D + rr * D + tcol];
        u16 h[4] = {f2bf(v.x), f2bf(v.y), f2bf(v.z), f2bf(v.w)};
        *(ushort4*)(Bs + trow * 128 + (((tcol >> 3) ^ (trow & 7)) << 3) + (tcol & 7))
            = *(ushort4*)h;
    }
    __syncthreads();

    // GEMM2: P-tile 64x64
    f32x4 acc2[2][2] = {};
    #pragma unroll
    for (int ks = 0; ks < 4; ++ks) {
        bf16x8 a[2], b[2];
        #pragma unroll
        for (int m = 0; m < 2; ++m) {
            int row = wr * 32 + m * 16 + l15;
            int c16 = ks * 4 + l4;
            a[m] = *(const bf16x8*)(As + row * 128 + ((c16 ^ (row & 7)) * 8));
        }
        #pragma unroll
        for (int n = 0; n < 2; ++n) {
            int row = wc * 32 + n * 16 + l15;
            int c16 = ks * 4 + l4;
            b[n] = *(const bf16x8*)(Bs + row * 128 + ((c16 ^ (row & 7)) * 8));
        }
        #pragma unroll
        for (int m = 0; m < 2; ++m)
            #pragma unroll
            for (int n = 0; n < 2; ++n)
                acc2[m][n] = __builtin_amdgcn_mfma_f32_16x16x32_bf16(
                    a[m], b[n], acc2[m][n], 0, 0, 0);
    }
    #pragma unroll
    for (int m = 0; m < 2; ++m)
        #pragma unroll
        for (int n = 0; n < 2; ++n)
            #pragma unroll
            for (int r = 0; r < 4; ++r) {
                int grow = bm + wr * 32 + m * 16 + l4 * 4 + r;
                int gcol = bn + wc * 32 + n * 16 + l15;
                if (gcol < PLD)
                    Pb[(size_t)grow * PLD + gcol] = f2bf(acc2[m][n][r] * SQRT_D_INV);
            }
}

// ------------------------------------------------------------------
// flash_kernel: grid (64 i-tiles, 8 j-chunks) -> XCD = i-tile % 8, so
// all j-chunks of an i-tile share one XCD's L2 copy of the P slab.
// ------------------------------------------------------------------
__global__ __launch_bounds__(256) void flash_kernel(
    const u16* __restrict__ qb,   // 1024x128 (pre-scaled)
    const u16* __restrict__ kb,   // 1024x128
    const u16* __restrict__ vT,   // 128x1024
    const u16* __restrict__ Pb,   // 1024x1200 bf16 (pre-scaled)
    const float* __restrict__ vd, // 1024x1024x3
    float* __restrict__ part,     // [8][1024][128]
    float* __restrict__ rowsumP)  // [8][1024]
{
    __shared__ __align__(16) u16 Pl[2432 * 8];   // 16x1200 + pad
    __shared__ __align__(16) u16 Ps[16 * 128];
    __shared__ float rsw[4][16];
    const int tid = threadIdx.x;
    const int wave = tid >> 6, lane = tid & 63;
    const int l15 = lane & 15, l4 = lane >> 4;
    const int bm = blockIdx.x * 16;     // i tile
    const int bn = blockIdx.y * 128;    // j chunk
    const int chunk = blockIdx.y;

    // ---- stage P slab ----
    const u16* Pg = Pb + (size_t)bm * PLD;
    #pragma unroll
    for (int r0 = 0; r0 < 9; ++r0) {
        int unit = r0 * 256 + tid;
        __builtin_amdgcn_global_load_lds(
            (const GLOBAL_AS unsigned int*)(Pg + unit * 8),
            (LDS_AS unsigned int*)(Pl + r0 * 2048 + wave * 512), 16, 0, 0);
    }
    if (wave < 2) {
        int unit = 9 * 256 + tid;
        int cu = unit > 2399 ? 2399 : unit;
        __builtin_amdgcn_global_load_lds(
            (const GLOBAL_AS unsigned int*)(Pg + cu * 8),
            (LDS_AS unsigned int*)(Pl + 9 * 2048 + wave * 512), 16, 0, 0);
    }

    // ---- early vd loads (T14) ----
    float vx[2][4], vy[2][4], vz[2][4];
    #pragma unroll
    for (int nn = 0; nn < 2; ++nn)
        #pragma unroll
        for (int r = 0; r < 4; ++r) {
            int i = l4 * 4 + r;
            int j = wave * 32 + nn * 16 + l15;
            const float* vp = vd + ((size_t)(bm + i) * N_PTS + bn + j) * 3;
            vx[nn][r] = vp[0]; vy[nn][r] = vp[1]; vz[nn][r] = vp[2];
        }

    // ---- QK^T ----
    bf16x8 aq[4];
    #pragma unroll
    for (int ks = 0; ks < 4; ++ks)
        aq[ks] = *(const bf16x8*)(qb + (size_t)(bm + l15) * D + ks * 32 + l4 * 8);
    f32x4 acc[2] = {};
    #pragma unroll
    for (int nn = 0; nn < 2; ++nn) {
        int jt = bn + wave * 32 + nn * 16;
        #pragma unroll
        for (int ks = 0; ks < 4; ++ks) {
            bf16x8 bk = *(const bf16x8*)(kb + (size_t)(jt + l15) * D + ks * 32 + l4 * 8);
            acc[nn] = __builtin_amdgcn_mfma_f32_16x16x32_bf16(aq[ks], bk, acc[nn], 0, 0, 0);
        }
    }
    __syncthreads();   // Pl staged

    // ---- bias gather + exp + Ps + rowsum ----
    float rs[4] = {0.f, 0.f, 0.f, 0.f};
    #pragma unroll
    for (int nn = 0; nn < 2; ++nn)
        #pragma unroll
        for (int r = 0; r < 4; ++r) {
            int i = l4 * 4 + r;
            int jl = wave * 32 + nn * 16 + l15;
            int ix = (int)floorf((vx[nn][r] + 4.0f) * 50.0f);
            int iy = (int)floorf((vy[nn][r] + 4.0f) * 50.0f);
            int iz = (int)floorf((vz[nn][r] + 4.0f) * 50.0f);
            ix = min(max(ix, 0), QL - 1);
            iy = min(max(iy, 0), QL - 1);
            iz = min(max(iz, 0), QL - 1);
            const u16* Pr = Pl + i * PLD;
            float bv = b2f(Pr[ix]) + b2f(Pr[QL + iy]) + b2f(Pr[2 * QL + iz]);
            float e = __expf(acc[nn][r] + bv);
            rs[r] += e;
            Ps[i * 128 + (((jl >> 3) ^ (i & 7)) * 8) + (jl & 7)] = f2bf(e);
        }
    #pragma unroll
    for (int r = 0; r < 4; ++r)
        #pragma unroll
        for (int off = 1; off < 16; off <<= 1)
            rs[r] += __shfl_xor(rs[r], off);
    if (l15 == 0)
        #pragma unroll
        for (int r = 0; r < 4; ++r) rsw[wave][l4 * 4 + r] = rs[r];
    __syncthreads();
    if (tid < 16)
        rowsumP[chunk * N_PTS + bm + tid] =
            rsw[0][tid] + rsw[1][tid] + rsw[2][tid] + rsw[3][tid];

    // ---- PV ----
    bf16x8 pa[4];
    #pragma unroll
    for (int kt = 0; kt < 4; ++kt)
        pa[kt] = *(const bf16x8*)(Ps + l15 * 128 + (((kt * 4 + l4) ^ (l15 & 7)) * 8));
    f32x4 acc2[2] = {};
    #pragma unroll
    for (int nn = 0; nn < 2; ++nn) {
        int dt = wave * 32 + nn * 16;
        #pragma unroll
        for (int kt = 0; kt < 4; ++kt) {
            bf16x8 bv8 = *(const bf16x8*)(vT + (size_t)(dt + l15) * N_PTS + bn + kt * 32 + l4 * 8);
            acc2[nn] = __builtin_amdgcn_mfma_f32_16x16x32_bf16(pa[kt], bv8, acc2[nn], 0, 0, 0);
        }
    }
    float* po = part + (size_t)chunk * (N_PTS * D);
    #pragma unroll
    for (int nn = 0; nn < 2; ++nn)
        #pragma unroll
        for (int r = 0; r < 4; ++r)
            po[(size_t)(bm + l4 * 4 + r) * D + wave * 32 + nn * 16 + l15] = acc2[nn][r];
}

// ------------------------------------------------------------------
// reduce partials + normalize (fixed order, deterministic)
// ------------------------------------------------------------------
__global__ __launch_bounds__(256) void reduce_norm_kernel(
    const float* __restrict__ part,      // [8][1024][128]
    const float* __restrict__ rowsumP,   // [8][1024]
    float* __restrict__ out)             // [1024][128]
{
    int e = blockIdx.x * 256 + threadIdx.x;   // float4 id, 32768 total
    int row = e >> 5;
    float rs = 0.0f;
    #pragma unroll
    for (int jb = 0; jb < 8; ++jb) rs += rowsumP[jb * N_PTS + row];
    float inv = 1.0f / rs;
    const float4* p4 = (const float4*)part;
    float4 a = p4[e];
    #pragma unroll
    for (int z = 1; z < 8; ++z) {
        float4 v = p4[(size_t)z * 32768 + e];
        a.x += v.x; a.y += v.y; a.z += v.z; a.w += v.w;
    }
    a.x *= inv; a.y *= inv; a.z *= inv; a.w *= inv;
    ((float4*)out)[e] = a;
}

// ------------------------------------------------------------------
extern "C" void kernel_launch(void* const* d_in, const int* in_sizes, int n_in,
                              void* d_out, int out_size, void* d_ws, size_t ws_size,
                              hipStream_t stream)
{
    const float* features = (const float*)d_in[0];  // 1024 x 128
    const float* vd       = (const float*)d_in[1];  // 1024 x 1024 x 3
    const float* W        = (const float*)d_in[2];  // 128 x 384
    const float* b        = (const float*)d_in[3];  // 384
    const float* tx       = (const float*)d_in[4];  // 3 x 400 x 128
    const float* ty       = (const float*)d_in[5];
    const float* tz       = (const float*)d_in[6];
    float* out = (float*)d_out;                     // 1024 x 128 f32

    char* w0 = (char*)d_ws;
    u16* qb       = (u16*)w0;                       // 256 KB
    u16* kb       = (u16*)(w0 + 0x40000);           // 256 KB
    u16* vT       = (u16*)(w0 + 0x80000);           // 256 KB (128x1024)
    u16* Pb       = (u16*)(w0 + 0xC0000);           // 2.4 MB (1024x1200 bf16)
    float* part   = (float*)(w0 + 0x320000);        // 4 MB   [8][1024][128]
    float* rowsumP= (float*)(w0 + 0x720000);        // 32 KB  [8][1024]

    dim3 blk(256);

    // 1. qkv + P, one dispatch (P-role blocks first; both roles read only inputs)
    prep_all_kernel<<<dim3(400), blk, 0, stream>>>(
        features, W, b, tx, ty, tz, qb, kb, vT, Pb);

    // 2. flash: S+bias+exp+PV partials (grid: i-tiles x j-chunks)
    flash_kernel<<<dim3(64, 8), blk, 0, stream>>>(
        qb, kb, vT, Pb, vd, part, rowsumP);

    // 3. reduce + normalize
    reduce_norm_kernel<<<dim3(128), blk, 0, stream>>>(part, rowsumP, out);
}